// Round 3
// baseline (1028.246 us; speedup 1.0000x reference)
//
#include <hip/hip_runtime.h>
#include <cstdint>

#define S_LEN 2048
#define DMODEL 2560
#define NHEADS 32
#define HDIM 80
#define DINTER 10240

typedef unsigned short u16;
typedef __bf16 bf16x8 __attribute__((ext_vector_type(8)));
typedef float f32x4 __attribute__((ext_vector_type(4)));

__device__ __forceinline__ float us2f(u16 u) {
  return __builtin_bit_cast(float, ((uint32_t)u) << 16);
}
__device__ __forceinline__ u16 f2us(float f) {
  uint32_t x = __builtin_bit_cast(uint32_t, f);
  x += 0x7fffu + ((x >> 16) & 1u);
  return (u16)(x >> 16);
}

typedef __attribute__((address_space(1))) void gas_void;
typedef __attribute__((address_space(3))) void las_void;
__device__ __forceinline__ void gld16(const void* g, void* l) {
  __builtin_amdgcn_global_load_lds((gas_void*)g, (las_void*)l, 16, 0, 0);
}

#define VMW(N) asm volatile("s_waitcnt vmcnt(" #N ")" ::: "memory")
#define BARRIER()                          \
  do {                                     \
    asm volatile("" ::: "memory");         \
    __builtin_amdgcn_s_barrier();          \
    asm volatile("" ::: "memory");         \
  } while (0)

// ---------------------------------------------------------------------------
// fp32 -> bf16 conversion, 8 elements/thread
// ---------------------------------------------------------------------------
__global__ void f2b_kernel(const float* __restrict__ src, u16* __restrict__ dst) {
  const size_t i = ((size_t)blockIdx.x * 256 + threadIdx.x) * 8;
  const float4 a = *(const float4*)(src + i);
  const float4 b = *(const float4*)(src + i + 4);
  u16 o[8] = {f2us(a.x), f2us(a.y), f2us(a.z), f2us(a.w),
              f2us(b.x), f2us(b.y), f2us(b.z), f2us(b.w)};
  *(uint4*)(dst + i) = *(uint4*)o;
}

// ---------------------------------------------------------------------------
// out = x + wo_b[col] + w2_b[col]  (fp32)
// ---------------------------------------------------------------------------
__global__ void initout_kernel(const float* __restrict__ x,
                               const float* __restrict__ wo_b,
                               const float* __restrict__ w2_b,
                               float* __restrict__ out) {
  const size_t idx = ((size_t)blockIdx.x * 256 + threadIdx.x) * 4;
  const int c0 = (int)(idx % DMODEL);
  const float4 vx = *(const float4*)(x + idx);
  const float4 b1 = *(const float4*)(wo_b + c0);
  const float4 b2 = *(const float4*)(w2_b + c0);
  float4 vo;
  vo.x = vx.x + b1.x + b2.x;
  vo.y = vx.y + b1.y + b2.y;
  vo.z = vx.z + b1.z + b2.z;
  vo.w = vx.w + b1.w + b2.w;
  *(float4*)(out + idx) = vo;
}

// ---------------------------------------------------------------------------
// LayerNorm: fp32 in, bf16 out. One block per row (2560 = 256 x 10)
// ---------------------------------------------------------------------------
__global__ void ln_kernel(const float* __restrict__ x, const float* __restrict__ w,
                          const float* __restrict__ b, u16* __restrict__ h) {
  const int s = blockIdx.x, tid = threadIdx.x;
  const float* xr = x + (size_t)s * DMODEL;
  float v[10];
  float sum = 0.f, sq = 0.f;
#pragma unroll
  for (int j = 0; j < 10; j++) {
    v[j] = xr[tid + j * 256];
    sum += v[j];
    sq += v[j] * v[j];
  }
#pragma unroll
  for (int o = 32; o > 0; o >>= 1) {
    sum += __shfl_down(sum, o, 64);
    sq += __shfl_down(sq, o, 64);
  }
  __shared__ float red[8];
  const int wave = tid >> 6, lane = tid & 63;
  if (lane == 0) { red[wave] = sum; red[4 + wave] = sq; }
  __syncthreads();
  sum = red[0] + red[1] + red[2] + red[3];
  sq = red[4] + red[5] + red[6] + red[7];
  const float mu = sum * (1.0f / DMODEL);
  const float var = sq * (1.0f / DMODEL) - mu * mu;
  const float rstd = rsqrtf(var + 1e-5f);
  u16* hr = h + (size_t)s * DMODEL;
#pragma unroll
  for (int j = 0; j < 10; j++) {
    const int d = tid + j * 256;
    hr[d] = f2us((v[j] - mu) * rstd * w[d] + b[d]);
  }
}

// ---------------------------------------------------------------------------
// 256x256 GEMM, BK=32, 4-deep LDS pipeline: C = act(A[M][K] * B[N][K]^T).
// 512 thr = 8 waves (2M x 4N); per-wave 128x64 out = 8mf x 4nf 16x16 frags.
// LDS = 4 buffers x (A 16KB + B 16KB) = 128 KiB; tile t lives in buf[t%4].
//
// Per K-tile, 2 phases (M-half each, 16 MFMA), ONE barrier + ONE counted
// vmcnt.  Every MFMA consumes operands ds_read a phase EARLIER, so the LDS
// pipe services reads while the matrix pipe drains (previous structure
// serialized them via same-phase lgkmcnt(0); MfmaUtil 24%):
//   ph0: ds_read A1(t)          | MFMA h0 (A0(t),B(t)) | VMW(4) | BARRIER
//   ph1: stage tile t+3 (4 gld) | ds_read A0(t+1),B(t+1) | MFMA h1 (A1(t),B(t))
// Ledger (4 gld/wave/tile, staged at ph1 for t+3): at TILE(u) ph0 the
// outstanding loads are {u+1, u+2} (8) -> VMW(4) retires u+1 (issued 3 tiles
// = ~4000cyc earlier; never stalls), which ph1 then reads.  VMW precedes the
// barrier so all waves' stages are complete & LDS-visible at release.
// WAR: staging into buf[(u+3)%4]=buf[(u-1)%4] is safe: barrier arrival =>
// every wave issued ph0 MFMAs => drained its tile-(u-1) ds_reads.
// Tail: VMW(0) when u+2 >= nt (those loads are a tile old -> cheap).
//
// BK=32 row stride = 64B, so a fragment ds_read_b128 (16 rows x 4 k-slots)
// covers a contiguous 1KB -> conflict-free with NO swizzle; staging is
// linear (global_load_lds dest = wave base + lane*16 = row-major exactly).
// grid.z = K-split; MODE: 0 bf16 store (+bias), 2 fp32 atomicAdd.
// ---------------------------------------------------------------------------
template <int ACT, int MODE>
__launch_bounds__(512, 2)
__global__ void gemm256(const u16* __restrict__ A, const u16* __restrict__ B,
                        const float* __restrict__ bias, void* __restrict__ Cv,
                        int M, int N, int K) {
  __shared__ __align__(16) u16 lds[4][16384];  // 4 x (A 8192 | B 8192) u16
  const int tid = threadIdx.x;
  const int w = tid >> 6, lane = tid & 63;
  const int quad = lane >> 4, l15 = lane & 15;
  const int wm = w >> 2, wn = w & 3;

  // XCD-aware bijective swizzle (nwg % 8 == 0 at all call sites)
  const int nwg = gridDim.x * gridDim.y;
  const int flat = blockIdx.x + gridDim.x * blockIdx.y;
  const int swz = (flat & 7) * (nwg >> 3) + (flat >> 3);
  const int ntN = N >> 8;
  const int bm = swz / ntN, bn = swz % ntN;

  const int Kc = K / gridDim.z;
  const int k0 = Kc * blockIdx.z;
  const int nt = Kc >> 5;  // K-tiles of 32 (even, >=4 at all call sites)

  // staging: thread covers row tid>>2 of a 128-row half, 16B chunk tid&3.
  // LDS dest is wave-uniform (w*512 u16); HW adds lane*16B -> row-major.
  const size_t k128 = (size_t)128 * K;
  const u16* Ag = A + ((size_t)(bm * 256 + (tid >> 2))) * K + k0 + (tid & 3) * 8;
  const u16* Bg = B + ((size_t)(bn * 256 + (tid >> 2))) * K + k0 + (tid & 3) * 8;
  const int wDst = w * 512;

  // ds_read bases (u16 units): frag mf at +mf*512 (+ph*2048), nf at +nf*512
  const int aRd = (wm * 128 + l15) * 32 + quad * 8;
  const int bRd = 8192 + (wn * 64 + l15) * 32 + quad * 8;

#define STAGE(W)                                                             \
  do {                                                                       \
    const int q_ = (W) & 3;                                                  \
    const size_t ko_ = (size_t)(W) * 32;                                     \
    gld16(Ag + ko_, &lds[q_][wDst]);                                         \
    gld16(Ag + k128 + ko_, &lds[q_][4096 + wDst]);                           \
    gld16(Bg + ko_, &lds[q_][8192 + wDst]);                                  \
    gld16(Bg + k128 + ko_, &lds[q_][12288 + wDst]);                          \
  } while (0)

#define LD_A(DST, QB, PH)                                                    \
  _Pragma("unroll") for (int mf_ = 0; mf_ < 4; mf_++)                        \
      DST[mf_] = *(const bf16x8*)&lds[QB][aRd + (PH) * 2048 + mf_ * 512];

#define LD_B(DST, QB)                                                        \
  _Pragma("unroll") for (int nf_ = 0; nf_ < 4; nf_++)                        \
      DST[nf_] = *(const bf16x8*)&lds[QB][bRd + nf_ * 512];

#define MFMA_HALF(PH, AF, BF)                                                \
  do {                                                                       \
    __builtin_amdgcn_s_setprio(1);                                           \
    _Pragma("unroll") for (int mf_ = 0; mf_ < 4; mf_++)                      \
    _Pragma("unroll") for (int nf_ = 0; nf_ < 4; nf_++)                      \
        acc[(PH) * 4 + mf_][nf_] = __builtin_amdgcn_mfma_f32_16x16x32_bf16(  \
            AF[mf_], BF[nf_], acc[(PH) * 4 + mf_][nf_], 0, 0, 0);            \
    __builtin_amdgcn_s_setprio(0);                                           \
  } while (0)

// TILE: aP0 holds A0(U) on entry (refreshed in ph1 to A0(U+1));
// BCUR = B(U); BNXT receives B(U+1).
#define TILE(U, BCUR, BNXT)                                                  \
  do {                                                                       \
    const int q_ = (U) & 3;                                                  \
    LD_A(aP1, q_, 1);                                                        \
    MFMA_HALF(0, aP0, BCUR);                                                 \
    if ((U) + 2 < nt) { VMW(4); } else { VMW(0); }                           \
    BARRIER();                                                               \
    if ((U) + 3 < nt) STAGE((U) + 3);                                        \
    if ((U) + 1 < nt) {                                                      \
      const int qn_ = ((U) + 1) & 3;                                         \
      LD_A(aP0, qn_, 0);                                                     \
      LD_B(BNXT, qn_);                                                       \
    }                                                                        \
    MFMA_HALF(1, aP1, BCUR);                                                 \
  } while (0)

  f32x4 acc[8][4] = {};
  bf16x8 aP0[4], aP1[4], bE[4], bO[4];

  // prologue: stage tiles 0..2, land tile 0, preload its ph0 operands
  STAGE(0);
  STAGE(1);
  STAGE(2);
  VMW(8);
  BARRIER();
  LD_A(aP0, 0, 0);
  LD_B(bE, 0);

  for (int u = 0; u < nt; u += 2) {
    TILE(u, bE, bO);
    TILE(u + 1, bO, bE);
  }

#pragma unroll
  for (int nf = 0; nf < 4; nf++) {
    const int col = bn * 256 + wn * 64 + nf * 16 + l15;
    const float bv = (MODE == 0) ? bias[col] : 0.f;
#pragma unroll
    for (int ph = 0; ph < 2; ph++)
#pragma unroll
      for (int mf = 0; mf < 4; mf++) {
        const int row0 = bm * 256 + wm * 128 + ph * 64 + mf * 16 + quad * 4;
#pragma unroll
        for (int r = 0; r < 4; r++) {
          float v = acc[ph * 4 + mf][nf][r] + bv;
          if (ACT == 1) {
            const float tt = v * (0.7978845608f + 0.0356774081f * v * v);
            v = 0.5f * v * (1.0f + tanhf(tt));
          }
          if (MODE == 0)
            ((u16*)Cv)[(size_t)(row0 + r) * N + col] = f2us(v);
          else
            atomicAdd((float*)Cv + (size_t)(row0 + r) * N + col, v);
        }
      }
  }
#undef STAGE
#undef LD_A
#undef LD_B
#undef MFMA_HALF
#undef TILE
}

// ---------------------------------------------------------------------------
// RoPE in-place on bf16 qkv (q and k sections, first 32 dims of each head).
// ---------------------------------------------------------------------------
__global__ void rope_kernel(u16* __restrict__ qkv, const int* __restrict__ pos) {
  const int idx = blockIdx.x * 256 + threadIdx.x;
  const int i = idx & 15;
  const int which = (idx >> 4) & 1;
  const int hh = (idx >> 5) & 31;
  const int s = idx >> 10;
  const float p = (float)pos[s];
  const float freq = p * expf(-0.57564627324851f * (float)i);
  float sn, c;
  sincosf(freq, &sn, &c);
  u16* base = qkv + (size_t)s * (3 * DMODEL) + which * DMODEL + hh * HDIM + i;
  const float t0 = us2f(base[0]), t1 = us2f(base[16]);
  base[0] = f2us(t0 * c - t1 * sn);
  base[16] = f2us(t1 * c + t0 * sn);
}

// ---------------------------------------------------------------------------
// Flash attention (causal), bf16. Grid (S/64, H), 256 thr = 4 waves; each
// wave owns 16 q-rows. KT=64 keys/iter. hd 80 padded to 96 for 3 K=32 MFMA
// steps. Conflict-free strides: Qs/Ks 104, Vts 88, Ps two 16x40 tiles.
// ---------------------------------------------------------------------------
__global__ void attn_kernel(const u16* __restrict__ qkv, u16* __restrict__ y) {
  const int qt = (int)gridDim.x - 1 - (int)blockIdx.x;  // longest first
  const int h = blockIdx.y;
  const int tid = threadIdx.x, wave = tid >> 6, lane = tid & 63;
  const int quad = lane >> 4, l15 = lane & 15;
  const int qbase = qt * 64;

  __shared__ __align__(16) u16 Qs[64 * 104];
  __shared__ __align__(16) u16 Ks[64 * 104];
  __shared__ __align__(16) u16 Vts[80 * 88];   // [dim][key], stride 88
  __shared__ __align__(16) u16 Ps[4][2][16 * 40];

  for (int i = tid; i < 64 * 104; i += 256) { Qs[i] = 0; Ks[i] = 0; }
  __syncthreads();

  {  // stage Q once, folding in 1/sqrt(80)
    const int r = tid >> 2, c = tid & 3;
    const u16* src = qkv + (size_t)(qbase + r) * (3 * DMODEL) + h * HDIM + c * 20;
    u16* dst = Qs + r * 104 + c * 20;
#pragma unroll
    for (int j = 0; j < 5; j++) {
      ushort4 uv = *(const ushort4*)(src + j * 4);
      ushort4 ov;
      ov.x = f2us(us2f(uv.x) * 0.11180339887f);
      ov.y = f2us(us2f(uv.y) * 0.11180339887f);
      ov.z = f2us(us2f(uv.z) * 0.11180339887f);
      ov.w = f2us(us2f(uv.w) * 0.11180339887f);
      *(ushort4*)(dst + j * 4) = ov;
    }
  }

  float m_i[4], l_i[4];
  f32x4 oacc[5] = {};
#pragma unroll
  for (int r = 0; r < 4; r++) { m_i[r] = -1e30f; l_i[r] = 0.f; }

  const int n_iter = qt + 1;
  __syncthreads();

  for (int it = 0; it < n_iter; ++it) {
    const int kc0 = it * 64;
    if (tid < 128) {  // waves 0-1: stage 64 K rows (2 threads/row)
      const int r = tid >> 1, c = (tid & 1) * 40;
      const u16* src =
          qkv + (size_t)(kc0 + r) * (3 * DMODEL) + DMODEL + h * HDIM + c;
      u16* dst = Ks + r * 104 + c;
#pragma unroll
      for (int j = 0; j < 10; j++)
        *(ushort4*)(dst + j * 4) = *(const ushort4*)(src + j * 4);
    } else {  // waves 2-3: stage 64 V rows transposed
      const int u = tid - 128;
      const int r = u >> 1, c0 = (u & 1) * 40;
      const u16* src =
          qkv + (size_t)(kc0 + r) * (3 * DMODEL) + 2 * DMODEL + h * HDIM + c0;
#pragma unroll
      for (int j = 0; j < 10; j++) {
        ushort4 vv = *(const ushort4*)(src + j * 4);
        const int d0 = c0 + j * 4;
        Vts[(d0 + 0) * 88 + r] = vv.x;
        Vts[(d0 + 1) * 88 + r] = vv.y;
        Vts[(d0 + 2) * 88 + r] = vv.z;
        Vts[(d0 + 3) * 88 + r] = vv.w;
      }
    }
    __syncthreads();

    // S = Q K^T : 16 rows x 64 cols per wave, 3 K-steps over padded hd=96
    f32x4 st[4] = {};
    bf16x8 aq[3];
#pragma unroll
    for (int ks = 0; ks < 3; ks++)
      aq[ks] = *(const bf16x8*)&Qs[(wave * 16 + l15) * 104 + ks * 32 + quad * 8];
#pragma unroll
    for (int ks = 0; ks < 3; ks++)
#pragma unroll
      for (int t = 0; t < 4; t++) {
        bf16x8 bk = *(const bf16x8*)&Ks[(t * 16 + l15) * 104 + ks * 32 + quad * 8];
        st[t] = __builtin_amdgcn_mfma_f32_16x16x32_bf16(aq[ks], bk, st[t], 0, 0, 0);
      }

    // causal mask + online softmax (rows = quad*4+r, cols = t*16+l15)
    float sv[4][4], mx[4];
#pragma unroll
    for (int r = 0; r < 4; r++) {
      const int qr = qbase + wave * 16 + quad * 4 + r;
#pragma unroll
      for (int t = 0; t < 4; t++) {
        const int kc = kc0 + t * 16 + l15;
        sv[t][r] = (kc <= qr) ? st[t][r] : -1e30f;
      }
      mx[r] = fmaxf(fmaxf(sv[0][r], sv[1][r]), fmaxf(sv[2][r], sv[3][r]));
    }
#pragma unroll
    for (int o = 1; o < 16; o <<= 1)
#pragma unroll
      for (int r = 0; r < 4; r++) mx[r] = fmaxf(mx[r], __shfl_xor(mx[r], o, 64));

    float alpha[4], rs[4];
#pragma unroll
    for (int r = 0; r < 4; r++) {
      const float mnew = fmaxf(m_i[r], mx[r]);
      alpha[r] = __expf(m_i[r] - mnew);
      m_i[r] = mnew;
      const float p0 = __expf(sv[0][r] - mnew);
      const float p1 = __expf(sv[1][r] - mnew);
      const float p2 = __expf(sv[2][r] - mnew);
      const float p3 = __expf(sv[3][r] - mnew);
      rs[r] = (p0 + p1) + (p2 + p3);
      const int ro = (quad * 4 + r) * 40;
      Ps[wave][0][ro + l15] = f2us(p0);
      Ps[wave][0][ro + 16 + l15] = f2us(p1);
      Ps[wave][1][ro + l15] = f2us(p2);
      Ps[wave][1][ro + 16 + l15] = f2us(p3);
    }
#pragma unroll
    for (int o = 1; o < 16; o <<= 1)
#pragma unroll
      for (int r = 0; r < 4; r++) rs[r] += __shfl_xor(rs[r], o, 64);
#pragma unroll
    for (int r = 0; r < 4; r++) l_i[r] = l_i[r] * alpha[r] + rs[r];
#pragma unroll
    for (int dt = 0; dt < 5; dt++)
#pragma unroll
      for (int r = 0; r < 4; r++) oacc[dt][r] *= alpha[r];

    // O += P V  (P via per-wave LDS round-trip into A-layout)
    bf16x8 pf0 = *(const bf16x8*)&Ps[wave][0][l15 * 40 + quad * 8];
    bf16x8 pf1 = *(const bf16x8*)&Ps[wave][1][l15 * 40 + quad * 8];
#pragma unroll
    for (int dt = 0; dt < 5; dt++) {
      bf16x8 vf0 = *(const bf16x8*)&Vts[(dt * 16 + l15) * 88 + quad * 8];
      bf16x8 vf1 = *(const bf16x8*)&Vts[(dt * 16 + l15) * 88 + 32 + quad * 8];
      oacc[dt] = __builtin_amdgcn_mfma_f32_16x16x32_bf16(pf0, vf0, oacc[dt], 0, 0, 0);
      oacc[dt] = __builtin_amdgcn_mfma_f32_16x16x32_bf16(pf1, vf1, oacc[dt], 0, 0, 0);
    }
    __syncthreads();
  }

#pragma unroll
  for (int dt = 0; dt < 5; dt++)
#pragma unroll
    for (int r = 0; r < 4; r++) {
      const int row = qbase + wave * 16 + quad * 4 + r;
      y[(size_t)row * DMODEL + h * HDIM + dt * 16 + l15] = f2us(oacc[dt][r] / l_i[r]);
    }
}

extern "C" void kernel_launch(void* const* d_in, const int* in_sizes, int n_in,
                              void* d_out, int out_size, void* d_ws, size_t ws_size,
                              hipStream_t stream) {
  const float* x = (const float*)d_in[0];
  const int* pos = (const int*)d_in[1];
  const float* ln_w = (const float*)d_in[3];
  const float* ln_b = (const float*)d_in[4];
  const float* wqkv_w = (const float*)d_in[5];
  const float* wqkv_b = (const float*)d_in[6];
  const float* wo_w = (const float*)d_in[7];
  const float* wo_b = (const float*)d_in[8];
  const float* w1_w = (const float*)d_in[9];
  const float* w1_b = (const float*)d_in[10];
  const float* w2_w = (const float*)d_in[11];
  const float* w2_b = (const float*)d_in[12];
  float* out = (float*)d_out;

  char* ws = (char*)d_ws;
  // layout (100 MB):
  //   [0,        52428800)  wbuf (bf16 weights, reused 4x)
  //   [52428800, 62914560)  h bf16
  //   [62914560, 104857600) ffn1 bf16 (42MB) -> later qkv (31.5) + yAtt (10.5)
  u16* wbuf = (u16*)(ws);
  u16* h = (u16*)(ws + 52428800);
  u16* ffn1 = (u16*)(ws + 62914560);
  u16* qkv = (u16*)(ws + 62914560);
  u16* yAtt = (u16*)(ws + 94371840);

  ln_kernel<<<S_LEN, 256, 0, stream>>>(x, ln_w, ln_b, h);
  initout_kernel<<<(S_LEN * DMODEL / 4) / 256, 256, 0, stream>>>(x, wo_b, w2_b, out);

  // FFN branch (ffn1 dies before qkv overlays it)
  f2b_kernel<<<(DINTER * DMODEL) / 2048, 256, 0, stream>>>(w1_w, wbuf);
  gemm256<1, 0><<<dim3(DINTER / 256, S_LEN / 256, 1), 512, 0, stream>>>(
      h, wbuf, w1_b, ffn1, S_LEN, DINTER, DMODEL);
  f2b_kernel<<<(DMODEL * DINTER) / 2048, 256, 0, stream>>>(w2_w, wbuf);
  gemm256<0, 2><<<dim3(DMODEL / 256, S_LEN / 256, 5), 512, 0, stream>>>(
      ffn1, wbuf, w2_b, out, S_LEN, DMODEL, DINTER);

  // Attention branch
  f2b_kernel<<<(3 * DMODEL * DMODEL) / 2048, 256, 0, stream>>>(wqkv_w, wbuf);
  gemm256<0, 0><<<dim3(3 * DMODEL / 256, S_LEN / 256, 1), 512, 0, stream>>>(
      h, wbuf, wqkv_b, qkv, S_LEN, 3 * DMODEL, DMODEL);
  rope_kernel<<<(S_LEN * NHEADS * 2 * 16) / 256, 256, 0, stream>>>(qkv, pos);
  attn_kernel<<<dim3(S_LEN / 64, NHEADS), 256, 0, stream>>>(qkv, yAtt);
  f2b_kernel<<<(DMODEL * DMODEL) / 2048, 256, 0, stream>>>(wo_w, wbuf);
  gemm256<0, 2><<<dim3(DMODEL / 256, S_LEN / 256, 2), 512, 0, stream>>>(
      yAtt, wbuf, wo_b, out, S_LEN, DMODEL, DMODEL);
}

// Round 5
// 976.025 us; speedup vs baseline: 1.0535x; 1.0535x over previous
//
#include <hip/hip_runtime.h>
#include <cstdint>

#define S_LEN 2048
#define DMODEL 2560
#define NHEADS 32
#define HDIM 80
#define DINTER 10240

typedef unsigned short u16;
typedef __bf16 bf16x8 __attribute__((ext_vector_type(8)));
typedef float f32x4 __attribute__((ext_vector_type(4)));

__device__ __forceinline__ float us2f(u16 u) {
  return __builtin_bit_cast(float, ((uint32_t)u) << 16);
}
__device__ __forceinline__ u16 f2us(float f) {
  uint32_t x = __builtin_bit_cast(uint32_t, f);
  x += 0x7fffu + ((x >> 16) & 1u);
  return (u16)(x >> 16);
}

typedef __attribute__((address_space(1))) void gas_void;
typedef __attribute__((address_space(3))) void las_void;
__device__ __forceinline__ void gld16(const void* g, void* l) {
  __builtin_amdgcn_global_load_lds((gas_void*)g, (las_void*)l, 16, 0, 0);
}

#define VMW(N) asm volatile("s_waitcnt vmcnt(" #N ")" ::: "memory")
#define BARRIER()                          \
  do {                                     \
    asm volatile("" ::: "memory");         \
    __builtin_amdgcn_s_barrier();          \
    asm volatile("" ::: "memory");         \
  } while (0)

// ---------------------------------------------------------------------------
// fp32 -> bf16 conversion, 8 elements/thread
// ---------------------------------------------------------------------------
__global__ void f2b_kernel(const float* __restrict__ src, u16* __restrict__ dst) {
  const size_t i = ((size_t)blockIdx.x * 256 + threadIdx.x) * 8;
  const float4 a = *(const float4*)(src + i);
  const float4 b = *(const float4*)(src + i + 4);
  u16 o[8] = {f2us(a.x), f2us(a.y), f2us(a.z), f2us(a.w),
              f2us(b.x), f2us(b.y), f2us(b.z), f2us(b.w)};
  *(uint4*)(dst + i) = *(uint4*)o;
}

// ---------------------------------------------------------------------------
// out = x + wo_b[col] + w2_b[col]  (fp32)
// ---------------------------------------------------------------------------
__global__ void initout_kernel(const float* __restrict__ x,
                               const float* __restrict__ wo_b,
                               const float* __restrict__ w2_b,
                               float* __restrict__ out) {
  const size_t idx = ((size_t)blockIdx.x * 256 + threadIdx.x) * 4;
  const int c0 = (int)(idx % DMODEL);
  const float4 vx = *(const float4*)(x + idx);
  const float4 b1 = *(const float4*)(wo_b + c0);
  const float4 b2 = *(const float4*)(w2_b + c0);
  float4 vo;
  vo.x = vx.x + b1.x + b2.x;
  vo.y = vx.y + b1.y + b2.y;
  vo.z = vx.z + b1.z + b2.z;
  vo.w = vx.w + b1.w + b2.w;
  *(float4*)(out + idx) = vo;
}

// ---------------------------------------------------------------------------
// LayerNorm: fp32 in, bf16 out. One block per row (2560 = 256 x 10)
// ---------------------------------------------------------------------------
__global__ void ln_kernel(const float* __restrict__ x, const float* __restrict__ w,
                          const float* __restrict__ b, u16* __restrict__ h) {
  const int s = blockIdx.x, tid = threadIdx.x;
  const float* xr = x + (size_t)s * DMODEL;
  float v[10];
  float sum = 0.f, sq = 0.f;
#pragma unroll
  for (int j = 0; j < 10; j++) {
    v[j] = xr[tid + j * 256];
    sum += v[j];
    sq += v[j] * v[j];
  }
#pragma unroll
  for (int o = 32; o > 0; o >>= 1) {
    sum += __shfl_down(sum, o, 64);
    sq += __shfl_down(sq, o, 64);
  }
  __shared__ float red[8];
  const int wave = tid >> 6, lane = tid & 63;
  if (lane == 0) { red[wave] = sum; red[4 + wave] = sq; }
  __syncthreads();
  sum = red[0] + red[1] + red[2] + red[3];
  sq = red[4] + red[5] + red[6] + red[7];
  const float mu = sum * (1.0f / DMODEL);
  const float var = sq * (1.0f / DMODEL) - mu * mu;
  const float rstd = rsqrtf(var + 1e-5f);
  u16* hr = h + (size_t)s * DMODEL;
#pragma unroll
  for (int j = 0; j < 10; j++) {
    const int d = tid + j * 256;
    hr[d] = f2us((v[j] - mu) * rstd * w[d] + b[d]);
  }
}

// ---------------------------------------------------------------------------
// 256x256 GEMM, BK=64, dbuf LDS, 2-barrier/2-vmcnt K-tile pipeline.
// C = act(A[M][K] * B[N][K]^T [+ bias]).  512 thr = 8 waves (2M x 4N),
// per-wave 128x64 out.  LDS 128 KiB: [b0A, b0B, b1A, b1B] x 32 KiB.
//
// Layout (verified zero-conflict, round 2): physical byte = logical ^
// ((row&7)<<4).  Pre-swizzled GLOBAL source (linear global_load_lds dest;
// lane's slot = (lane&7)^((lane>>3)&7)) + swizzled ds_read col
// ((kk*32+quad*8)^((l15&7)*8)).
//
// Schedule per tile t (clusters C1=(0,0) C2=(0,1) C3=(1,1) C4=(1,0); each
// cluster's ds_reads issue a phase before its MFMA so MFMA never waits on
// same-phase LDS; only P1/P4 have barriers, so waves skew through P1-P3):
//   P1: VMW(0) BAR | stage A0,B0(t+1) | ds_read bH1(t) | MFMA C1
//   P2:            | stage B1(t+1)    | ds_read aH1(t) | MFMA C2
//   P3:            | stage A1(t+1)    |                | MFMA C3
//   P4: VMW(4) BAR | MFMA C4 | ds_read aH0,bH0(t+1)  <-- prefetch AFTER C4:
//       C4 consumes bH0(t); writing it before C4 was the round-4 bug
//       (absmax 8.2: every C4 used B0 of t+1).  The ds_reads issue under
//       C4's ~260cy matrix-pipe drain; lgkm wait lands at C1(t+1).
// Ledger (per wave, VMW before BAR so all waves' staging is LDS-visible):
// VMW(0)@P1 retires B1,A1(t) (staged P2/P3(t-1)); VMW(4)@P4 retires
// A0,B0(t+1) (staged P1(t)), leaves B1,A1(t+1) in flight.
// WAR (LDS): each region is rewritten >=1 barrier after its last consuming
// ds_read drained (lgkm waits precede the prior tile's MFMAs).
// Registers: bH0/aH0 rewritten at P4(t) after C4(t) issue; read C1(t+1).
// grid.z = K-split; MODE: 0 bf16 store (+bias), 2 fp32 atomicAdd.
// ---------------------------------------------------------------------------
template <int ACT, int MODE>
__launch_bounds__(512, 2)
__global__ void gemm256(const u16* __restrict__ A, const u16* __restrict__ B,
                        const float* __restrict__ bias, void* __restrict__ Cv,
                        int M, int N, int K) {
  __shared__ __align__(16) u16 lds[4][16384];  // 128 KiB
  const int tid = threadIdx.x;
  const int w = tid >> 6, lane = tid & 63;
  const int quad = lane >> 4, l15 = lane & 15;
  const int wm = w >> 2, wn = w & 3;

  // XCD-aware bijective swizzle (nwg % 8 == 0 at all call sites)
  const int nwg = gridDim.x * gridDim.y;
  const int flat = blockIdx.x + gridDim.x * blockIdx.y;
  const int swz = (flat & 7) * (nwg >> 3) + (flat >> 3);
  const int ntN = N >> 8;
  const int bm = swz / ntN, bn = swz % ntN;

  const int Kc = K / gridDim.z;
  const int k0 = Kc * blockIdx.z;
  const int nt = Kc >> 6;  // K-tiles of 64 (>=20 at all call sites)

  // staging: lane covers row (w*8 + lane>>3) of a 64-row quarter; source
  // column pre-swizzled so linear LDS write == swizzled layout
  const int stgCol = (((lane & 7) ^ ((lane >> 3) & 7)) * 8);
  const u16* Ag = A + ((size_t)bm * 256 + w * 8 + (lane >> 3)) * K + k0 + stgCol;
  const u16* Bg = B + ((size_t)bn * 256 + w * 8 + (lane >> 3)) * K + k0 + stgCol;

  // ds_read swizzle terms (row&7 == l15&7 for every fragment row)
  const int q8 = quad * 8;
  const int swz3 = (l15 & 7) * 8;
  const int arow = wm * 64 + l15;
  const int brow = wn * 32 + l15;

#define STG_HALF(MAT, GP, BUF, HF, KT)                                       \
  do {                                                                       \
    gld16((GP) + (size_t)((HF) * 128) * K + (size_t)(KT) * 64,               \
          &lds[(BUF) * 2 + (MAT)][(HF) * 8192 + w * 512]);                   \
    gld16((GP) + (size_t)((HF) * 128 + 64) * K + (size_t)(KT) * 64,          \
          &lds[(BUF) * 2 + (MAT)][(HF) * 8192 + 4096 + w * 512]);            \
  } while (0)

#define LDS_A(DST, BUF, MH)                                                  \
  _Pragma("unroll") for (int mf_ = 0; mf_ < 4; mf_++)                        \
  _Pragma("unroll") for (int kk_ = 0; kk_ < 2; kk_++)                        \
      DST[mf_][kk_] = *(const bf16x8*)&lds[(BUF) * 2]                        \
          [(arow + (MH) * 128 + mf_ * 16) * 64 + ((kk_ * 32 + q8) ^ swz3)];

#define LDS_B(DST, BUF, NH)                                                  \
  _Pragma("unroll") for (int nf_ = 0; nf_ < 2; nf_++)                        \
  _Pragma("unroll") for (int kk_ = 0; kk_ < 2; kk_++)                        \
      DST[nf_][kk_] = *(const bf16x8*)&lds[(BUF) * 2 + 1]                    \
          [(brow + (NH) * 128 + nf_ * 16) * 64 + ((kk_ * 32 + q8) ^ swz3)];

#define MFMA_C(MH, NH, AF, BF)                                               \
  do {                                                                       \
    __builtin_amdgcn_s_setprio(1);                                           \
    _Pragma("unroll") for (int kk_ = 0; kk_ < 2; kk_++)                      \
    _Pragma("unroll") for (int mf_ = 0; mf_ < 4; mf_++)                      \
    _Pragma("unroll") for (int nf_ = 0; nf_ < 2; nf_++)                      \
        acc[(MH) * 4 + mf_][(NH) * 2 + nf_] =                                \
            __builtin_amdgcn_mfma_f32_16x16x32_bf16(                         \
                AF[mf_][kk_], BF[nf_][kk_],                                  \
                acc[(MH) * 4 + mf_][(NH) * 2 + nf_], 0, 0, 0);               \
    __builtin_amdgcn_s_setprio(0);                                           \
  } while (0)

  f32x4 acc[8][4] = {};
  bf16x8 aH0[4][2], aH1[4][2], bH0[2][2], bH1[2][2];

  // prologue: stage tile0 (A0,B0,B1,A1); release A0,B0; preload C1 operands
  STG_HALF(0, Ag, 0, 0, 0);
  STG_HALF(1, Bg, 0, 0, 0);
  STG_HALF(1, Bg, 0, 1, 0);
  STG_HALF(0, Ag, 0, 1, 0);
  VMW(4);
  BARRIER();
  LDS_A(aH0, 0, 0);
  LDS_B(bH0, 0, 0);

  for (int t = 0; t < nt; ++t) {
    const int bc = t & 1, ob = bc ^ 1;
    const bool more = (t + 1 < nt);
    // P1: release B1,A1(t) for all waves
    VMW(0);
    BARRIER();
    if (more) {
      STG_HALF(0, Ag, ob, 0, t + 1);
      STG_HALF(1, Bg, ob, 0, t + 1);
    }
    LDS_B(bH1, bc, 1);
    MFMA_C(0, 0, aH0, bH0);
    // P2
    if (more) STG_HALF(1, Bg, ob, 1, t + 1);
    LDS_A(aH1, bc, 1);
    MFMA_C(0, 1, aH0, bH1);
    // P3
    if (more) STG_HALF(0, Ag, ob, 1, t + 1);
    MFMA_C(1, 1, aH1, bH1);
    // P4: release A0,B0(t+1); C4 FIRST (consumes bH0(t)), then prefetch
    // C1(t+1) operands into aH0/bH0 under C4's pipe drain.
    VMW(4);
    BARRIER();
    MFMA_C(1, 0, aH1, bH0);
    if (more) {
      LDS_A(aH0, ob, 0);
      LDS_B(bH0, ob, 0);
    }
  }

#pragma unroll
  for (int nh = 0; nh < 2; nh++)
#pragma unroll
    for (int nf = 0; nf < 2; nf++) {
      const int col = bn * 256 + nh * 128 + wn * 32 + nf * 16 + l15;
      const float bv = (MODE == 0) ? bias[col] : 0.f;
#pragma unroll
      for (int mh = 0; mh < 2; mh++)
#pragma unroll
        for (int mf = 0; mf < 4; mf++) {
          const int row0 = bm * 256 + mh * 128 + wm * 64 + mf * 16 + quad * 4;
#pragma unroll
          for (int r = 0; r < 4; r++) {
            float v = acc[mh * 4 + mf][nh * 2 + nf][r] + bv;
            if (ACT == 1) {
              const float tt = v * (0.7978845608f + 0.0356774081f * v * v);
              v = 0.5f * v * (1.0f + tanhf(tt));
            }
            if (MODE == 0)
              ((u16*)Cv)[(size_t)(row0 + r) * N + col] = f2us(v);
            else
              atomicAdd((float*)Cv + (size_t)(row0 + r) * N + col, v);
          }
        }
    }
#undef STG_HALF
#undef LDS_A
#undef LDS_B
#undef MFMA_C
}

// ---------------------------------------------------------------------------
// RoPE in-place on bf16 qkv (q and k sections, first 32 dims of each head).
// ---------------------------------------------------------------------------
__global__ void rope_kernel(u16* __restrict__ qkv, const int* __restrict__ pos) {
  const int idx = blockIdx.x * 256 + threadIdx.x;
  const int i = idx & 15;
  const int which = (idx >> 4) & 1;
  const int hh = (idx >> 5) & 31;
  const int s = idx >> 10;
  const float p = (float)pos[s];
  const float freq = p * expf(-0.57564627324851f * (float)i);
  float sn, c;
  sincosf(freq, &sn, &c);
  u16* base = qkv + (size_t)s * (3 * DMODEL) + which * DMODEL + hh * HDIM + i;
  const float t0 = us2f(base[0]), t1 = us2f(base[16]);
  base[0] = f2us(t0 * c - t1 * sn);
  base[16] = f2us(t1 * c + t0 * sn);
}

// ---------------------------------------------------------------------------
// Flash attention (causal), bf16. Grid (S/64, H), 256 thr = 4 waves; each
// wave owns 16 q-rows. KT=64 keys/iter. hd 80 padded to 96 for 3 K=32 MFMA
// steps. Conflict-free strides: Qs/Ks 104, Vts 88, Ps two 16x40 tiles.
// ---------------------------------------------------------------------------
__global__ void attn_kernel(const u16* __restrict__ qkv, u16* __restrict__ y) {
  const int qt = (int)gridDim.x - 1 - (int)blockIdx.x;  // longest first
  const int h = blockIdx.y;
  const int tid = threadIdx.x, wave = tid >> 6, lane = tid & 63;
  const int quad = lane >> 4, l15 = lane & 15;
  const int qbase = qt * 64;

  __shared__ __align__(16) u16 Qs[64 * 104];
  __shared__ __align__(16) u16 Ks[64 * 104];
  __shared__ __align__(16) u16 Vts[80 * 88];   // [dim][key], stride 88
  __shared__ __align__(16) u16 Ps[4][2][16 * 40];

  for (int i = tid; i < 64 * 104; i += 256) { Qs[i] = 0; Ks[i] = 0; }
  __syncthreads();

  {  // stage Q once, folding in 1/sqrt(80)
    const int r = tid >> 2, c = tid & 3;
    const u16* src = qkv + (size_t)(qbase + r) * (3 * DMODEL) + h * HDIM + c * 20;
    u16* dst = Qs + r * 104 + c * 20;
#pragma unroll
    for (int j = 0; j < 5; j++) {
      ushort4 uv = *(const ushort4*)(src + j * 4);
      ushort4 ov;
      ov.x = f2us(us2f(uv.x) * 0.11180339887f);
      ov.y = f2us(us2f(uv.y) * 0.11180339887f);
      ov.z = f2us(us2f(uv.z) * 0.11180339887f);
      ov.w = f2us(us2f(uv.w) * 0.11180339887f);
      *(ushort4*)(dst + j * 4) = ov;
    }
  }

  float m_i[4], l_i[4];
  f32x4 oacc[5] = {};
#pragma unroll
  for (int r = 0; r < 4; r++) { m_i[r] = -1e30f; l_i[r] = 0.f; }

  const int n_iter = qt + 1;
  __syncthreads();

  for (int it = 0; it < n_iter; ++it) {
    const int kc0 = it * 64;
    if (tid < 128) {  // waves 0-1: stage 64 K rows (2 threads/row)
      const int r = tid >> 1, c = (tid & 1) * 40;
      const u16* src =
          qkv + (size_t)(kc0 + r) * (3 * DMODEL) + DMODEL + h * HDIM + c;
      u16* dst = Ks + r * 104 + c;
#pragma unroll
      for (int j = 0; j < 10; j++)
        *(ushort4*)(dst + j * 4) = *(const ushort4*)(src + j * 4);
    } else {  // waves 2-3: stage 64 V rows transposed
      const int u = tid - 128;
      const int r = u >> 1, c0 = (u & 1) * 40;
      const u16* src =
          qkv + (size_t)(kc0 + r) * (3 * DMODEL) + 2 * DMODEL + h * HDIM + c0;
#pragma unroll
      for (int j = 0; j < 10; j++) {
        ushort4 vv = *(const ushort4*)(src + j * 4);
        const int d0 = c0 + j * 4;
        Vts[(d0 + 0) * 88 + r] = vv.x;
        Vts[(d0 + 1) * 88 + r] = vv.y;
        Vts[(d0 + 2) * 88 + r] = vv.z;
        Vts[(d0 + 3) * 88 + r] = vv.w;
      }
    }
    __syncthreads();

    // S = Q K^T : 16 rows x 64 cols per wave, 3 K-steps over padded hd=96
    f32x4 st[4] = {};
    bf16x8 aq[3];
#pragma unroll
    for (int ks = 0; ks < 3; ks++)
      aq[ks] = *(const bf16x8*)&Qs[(wave * 16 + l15) * 104 + ks * 32 + quad * 8];
#pragma unroll
    for (int ks = 0; ks < 3; ks++)
#pragma unroll
      for (int t = 0; t < 4; t++) {
        bf16x8 bk = *(const bf16x8*)&Ks[(t * 16 + l15) * 104 + ks * 32 + quad * 8];
        st[t] = __builtin_amdgcn_mfma_f32_16x16x32_bf16(aq[ks], bk, st[t], 0, 0, 0);
      }

    // causal mask + online softmax (rows = quad*4+r, cols = t*16+l15)
    float sv[4][4], mx[4];
#pragma unroll
    for (int r = 0; r < 4; r++) {
      const int qr = qbase + wave * 16 + quad * 4 + r;
#pragma unroll
      for (int t = 0; t < 4; t++) {
        const int kc = kc0 + t * 16 + l15;
        sv[t][r] = (kc <= qr) ? st[t][r] : -1e30f;
      }
      mx[r] = fmaxf(fmaxf(sv[0][r], sv[1][r]), fmaxf(sv[2][r], sv[3][r]));
    }
#pragma unroll
    for (int o = 1; o < 16; o <<= 1)
#pragma unroll
      for (int r = 0; r < 4; r++) mx[r] = fmaxf(mx[r], __shfl_xor(mx[r], o, 64));

    float alpha[4], rs[4];
#pragma unroll
    for (int r = 0; r < 4; r++) {
      const float mnew = fmaxf(m_i[r], mx[r]);
      alpha[r] = __expf(m_i[r] - mnew);
      m_i[r] = mnew;
      const float p0 = __expf(sv[0][r] - mnew);
      const float p1 = __expf(sv[1][r] - mnew);
      const float p2 = __expf(sv[2][r] - mnew);
      const float p3 = __expf(sv[3][r] - mnew);
      rs[r] = (p0 + p1) + (p2 + p3);
      const int ro = (quad * 4 + r) * 40;
      Ps[wave][0][ro + l15] = f2us(p0);
      Ps[wave][0][ro + 16 + l15] = f2us(p1);
      Ps[wave][1][ro + l15] = f2us(p2);
      Ps[wave][1][ro + 16 + l15] = f2us(p3);
    }
#pragma unroll
    for (int o = 1; o < 16; o <<= 1)
#pragma unroll
      for (int r = 0; r < 4; r++) rs[r] += __shfl_xor(rs[r], o, 64);
#pragma unroll
    for (int r = 0; r < 4; r++) l_i[r] = l_i[r] * alpha[r] + rs[r];
#pragma unroll
    for (int dt = 0; dt < 5; dt++)
#pragma unroll
      for (int r = 0; r < 4; r++) oacc[dt][r] *= alpha[r];

    // O += P V  (P via per-wave LDS round-trip into A-layout)
    bf16x8 pf0 = *(const bf16x8*)&Ps[wave][0][l15 * 40 + quad * 8];
    bf16x8 pf1 = *(const bf16x8*)&Ps[wave][1][l15 * 40 + quad * 8];
#pragma unroll
    for (int dt = 0; dt < 5; dt++) {
      bf16x8 vf0 = *(const bf16x8*)&Vts[(dt * 16 + l15) * 88 + quad * 8];
      bf16x8 vf1 = *(const bf16x8*)&Vts[(dt * 16 + l15) * 88 + 32 + quad * 8];
      oacc[dt] = __builtin_amdgcn_mfma_f32_16x16x32_bf16(pf0, vf0, oacc[dt], 0, 0, 0);
      oacc[dt] = __builtin_amdgcn_mfma_f32_16x16x32_bf16(pf1, vf1, oacc[dt], 0, 0, 0);
    }
    __syncthreads();
  }

#pragma unroll
  for (int dt = 0; dt < 5; dt++)
#pragma unroll
    for (int r = 0; r < 4; r++) {
      const int row = qbase + wave * 16 + quad * 4 + r;
      y[(size_t)row * DMODEL + h * HDIM + dt * 16 + l15] = f2us(oacc[dt][r] / l_i[r]);
    }
}

extern "C" void kernel_launch(void* const* d_in, const int* in_sizes, int n_in,
                              void* d_out, int out_size, void* d_ws, size_t ws_size,
                              hipStream_t stream) {
  const float* x = (const float*)d_in[0];
  const int* pos = (const int*)d_in[1];
  const float* ln_w = (const float*)d_in[3];
  const float* ln_b = (const float*)d_in[4];
  const float* wqkv_w = (const float*)d_in[5];
  const float* wqkv_b = (const float*)d_in[6];
  const float* wo_w = (const float*)d_in[7];
  const float* wo_b = (const float*)d_in[8];
  const float* w1_w = (const float*)d_in[9];
  const float* w1_b = (const float*)d_in[10];
  const float* w2_w = (const float*)d_in[11];
  const float* w2_b = (const float*)d_in[12];
  float* out = (float*)d_out;

  char* ws = (char*)d_ws;
  // layout (100 MB):
  //   [0,        52428800)  wbuf (bf16 weights, reused 4x)
  //   [52428800, 62914560)  h bf16
  //   [62914560, 104857600) ffn1 bf16 (42MB) -> later qkv (31.5) + yAtt (10.5)
  u16* wbuf = (u16*)(ws);
  u16* h = (u16*)(ws + 52428800);
  u16* ffn1 = (u16*)(ws + 62914560);
  u16* qkv = (u16*)(ws + 62914560);
  u16* yAtt = (u16*)(ws + 94371840);

  ln_kernel<<<S_LEN, 256, 0, stream>>>(x, ln_w, ln_b, h);
  initout_kernel<<<(S_LEN * DMODEL / 4) / 256, 256, 0, stream>>>(x, wo_b, w2_b, out);

  // FFN branch (ffn1 dies before qkv overlays it)
  f2b_kernel<<<(DINTER * DMODEL) / 2048, 256, 0, stream>>>(w1_w, wbuf);
  gemm256<1, 0><<<dim3(DINTER / 256, S_LEN / 256, 1), 512, 0, stream>>>(
      h, wbuf, w1_b, ffn1, S_LEN, DINTER, DMODEL);
  f2b_kernel<<<(DMODEL * DINTER) / 2048, 256, 0, stream>>>(w2_w, wbuf);
  gemm256<0, 2><<<dim3(DMODEL / 256, S_LEN / 256, 5), 512, 0, stream>>>(
      ffn1, wbuf, w2_b, out, S_LEN, DMODEL, DINTER);

  // Attention branch
  f2b_kernel<<<(3 * DMODEL * DMODEL) / 2048, 256, 0, stream>>>(wqkv_w, wbuf);
  gemm256<0, 0><<<dim3(3 * DMODEL / 256, S_LEN / 256, 1), 512, 0, stream>>>(
      h, wbuf, wqkv_b, qkv, S_LEN, 3 * DMODEL, DMODEL);
  rope_kernel<<<(S_LEN * NHEADS * 2 * 16) / 256, 256, 0, stream>>>(qkv, pos);
  attn_kernel<<<dim3(S_LEN / 64, NHEADS), 256, 0, stream>>>(qkv, yAtt);
  f2b_kernel<<<(DMODEL * DMODEL) / 2048, 256, 0, stream>>>(wo_w, wbuf);
  gemm256<0, 2><<<dim3(DMODEL / 256, S_LEN / 256, 2), 512, 0, stream>>>(
      yAtt, wbuf, wo_b, out, S_LEN, DMODEL, DMODEL);
}

// Round 7
// 959.570 us; speedup vs baseline: 1.0716x; 1.0171x over previous
//
#include <hip/hip_runtime.h>
#include <cstdint>

#define S_LEN 2048
#define DMODEL 2560
#define NHEADS 32
#define HDIM 80
#define DINTER 10240

typedef unsigned short u16;
typedef __bf16 bf16x8 __attribute__((ext_vector_type(8)));
typedef float f32x4 __attribute__((ext_vector_type(4)));

__device__ __forceinline__ float us2f(u16 u) {
  return __builtin_bit_cast(float, ((uint32_t)u) << 16);
}
__device__ __forceinline__ u16 f2us(float f) {
  uint32_t x = __builtin_bit_cast(uint32_t, f);
  x += 0x7fffu + ((x >> 16) & 1u);
  return (u16)(x >> 16);
}

typedef __attribute__((address_space(1))) void gas_void;
typedef __attribute__((address_space(3))) void las_void;
__device__ __forceinline__ void gld16(const void* g, void* l) {
  __builtin_amdgcn_global_load_lds((gas_void*)g, (las_void*)l, 16, 0, 0);
}

#define VMW(N) asm volatile("s_waitcnt vmcnt(" #N ")" ::: "memory")
#define BARRIER()                          \
  do {                                     \
    asm volatile("" ::: "memory");         \
    __builtin_amdgcn_s_barrier();          \
    asm volatile("" ::: "memory");         \
  } while (0)

// ---------------------------------------------------------------------------
// fp32 -> bf16 conversion, 8 elements/thread
// ---------------------------------------------------------------------------
__global__ void f2b_kernel(const float* __restrict__ src, u16* __restrict__ dst) {
  const size_t i = ((size_t)blockIdx.x * 256 + threadIdx.x) * 8;
  const float4 a = *(const float4*)(src + i);
  const float4 b = *(const float4*)(src + i + 4);
  u16 o[8] = {f2us(a.x), f2us(a.y), f2us(a.z), f2us(a.w),
              f2us(b.x), f2us(b.y), f2us(b.z), f2us(b.w)};
  *(uint4*)(dst + i) = *(uint4*)o;
}

// ---------------------------------------------------------------------------
// out = x + wo_b[col] + w2_b[col]  (fp32)
// ---------------------------------------------------------------------------
__global__ void initout_kernel(const float* __restrict__ x,
                               const float* __restrict__ wo_b,
                               const float* __restrict__ w2_b,
                               float* __restrict__ out) {
  const size_t idx = ((size_t)blockIdx.x * 256 + threadIdx.x) * 4;
  const int c0 = (int)(idx % DMODEL);
  const float4 vx = *(const float4*)(x + idx);
  const float4 b1 = *(const float4*)(wo_b + c0);
  const float4 b2 = *(const float4*)(w2_b + c0);
  float4 vo;
  vo.x = vx.x + b1.x + b2.x;
  vo.y = vx.y + b1.y + b2.y;
  vo.z = vx.z + b1.z + b2.z;
  vo.w = vx.w + b1.w + b2.w;
  *(float4*)(out + idx) = vo;
}

// ---------------------------------------------------------------------------
// LayerNorm: fp32 in, bf16 out. One block per row (2560 = 256 x 10)
// ---------------------------------------------------------------------------
__global__ void ln_kernel(const float* __restrict__ x, const float* __restrict__ w,
                          const float* __restrict__ b, u16* __restrict__ h) {
  const int s = blockIdx.x, tid = threadIdx.x;
  const float* xr = x + (size_t)s * DMODEL;
  float v[10];
  float sum = 0.f, sq = 0.f;
#pragma unroll
  for (int j = 0; j < 10; j++) {
    v[j] = xr[tid + j * 256];
    sum += v[j];
    sq += v[j] * v[j];
  }
#pragma unroll
  for (int o = 32; o > 0; o >>= 1) {
    sum += __shfl_down(sum, o, 64);
    sq += __shfl_down(sq, o, 64);
  }
  __shared__ float red[8];
  const int wave = tid >> 6, lane = tid & 63;
  if (lane == 0) { red[wave] = sum; red[4 + wave] = sq; }
  __syncthreads();
  sum = red[0] + red[1] + red[2] + red[3];
  sq = red[4] + red[5] + red[6] + red[7];
  const float mu = sum * (1.0f / DMODEL);
  const float var = sq * (1.0f / DMODEL) - mu * mu;
  const float rstd = rsqrtf(var + 1e-5f);
  u16* hr = h + (size_t)s * DMODEL;
#pragma unroll
  for (int j = 0; j < 10; j++) {
    const int d = tid + j * 256;
    hr[d] = f2us((v[j] - mu) * rstd * w[d] + b[d]);
  }
}

// ---------------------------------------------------------------------------
// 256x256 GEMM, BK=64, dbuf LDS, 2-barrier/2-vmcnt K-tile pipeline.
// (unchanged from round 5 — passing, 0 bank conflicts, steady-state <175us)
// ---------------------------------------------------------------------------
template <int ACT, int MODE>
__launch_bounds__(512, 2)
__global__ void gemm256(const u16* __restrict__ A, const u16* __restrict__ B,
                        const float* __restrict__ bias, void* __restrict__ Cv,
                        int M, int N, int K) {
  __shared__ __align__(16) u16 lds[4][16384];  // 128 KiB
  const int tid = threadIdx.x;
  const int w = tid >> 6, lane = tid & 63;
  const int quad = lane >> 4, l15 = lane & 15;
  const int wm = w >> 2, wn = w & 3;

  const int nwg = gridDim.x * gridDim.y;
  const int flat = blockIdx.x + gridDim.x * blockIdx.y;
  const int swz = (flat & 7) * (nwg >> 3) + (flat >> 3);
  const int ntN = N >> 8;
  const int bm = swz / ntN, bn = swz % ntN;

  const int Kc = K / gridDim.z;
  const int k0 = Kc * blockIdx.z;
  const int nt = Kc >> 6;

  const int stgCol = (((lane & 7) ^ ((lane >> 3) & 7)) * 8);
  const u16* Ag = A + ((size_t)bm * 256 + w * 8 + (lane >> 3)) * K + k0 + stgCol;
  const u16* Bg = B + ((size_t)bn * 256 + w * 8 + (lane >> 3)) * K + k0 + stgCol;

  const int q8 = quad * 8;
  const int swz3 = (l15 & 7) * 8;
  const int arow = wm * 64 + l15;
  const int brow = wn * 32 + l15;

#define STG_HALF(MAT, GP, BUF, HF, KT)                                       \
  do {                                                                       \
    gld16((GP) + (size_t)((HF) * 128) * K + (size_t)(KT) * 64,               \
          &lds[(BUF) * 2 + (MAT)][(HF) * 8192 + w * 512]);                   \
    gld16((GP) + (size_t)((HF) * 128 + 64) * K + (size_t)(KT) * 64,          \
          &lds[(BUF) * 2 + (MAT)][(HF) * 8192 + 4096 + w * 512]);            \
  } while (0)

#define LDS_A(DST, BUF, MH)                                                  \
  _Pragma("unroll") for (int mf_ = 0; mf_ < 4; mf_++)                        \
  _Pragma("unroll") for (int kk_ = 0; kk_ < 2; kk_++)                        \
      DST[mf_][kk_] = *(const bf16x8*)&lds[(BUF) * 2]                        \
          [(arow + (MH) * 128 + mf_ * 16) * 64 + ((kk_ * 32 + q8) ^ swz3)];

#define LDS_B(DST, BUF, NH)                                                  \
  _Pragma("unroll") for (int nf_ = 0; nf_ < 2; nf_++)                        \
  _Pragma("unroll") for (int kk_ = 0; kk_ < 2; kk_++)                        \
      DST[nf_][kk_] = *(const bf16x8*)&lds[(BUF) * 2 + 1]                    \
          [(brow + (NH) * 128 + nf_ * 16) * 64 + ((kk_ * 32 + q8) ^ swz3)];

#define MFMA_C(MH, NH, AF, BF)                                               \
  do {                                                                       \
    __builtin_amdgcn_s_setprio(1);                                           \
    _Pragma("unroll") for (int kk_ = 0; kk_ < 2; kk_++)                      \
    _Pragma("unroll") for (int mf_ = 0; mf_ < 4; mf_++)                      \
    _Pragma("unroll") for (int nf_ = 0; nf_ < 2; nf_++)                      \
        acc[(MH) * 4 + mf_][(NH) * 2 + nf_] =                                \
            __builtin_amdgcn_mfma_f32_16x16x32_bf16(                         \
                AF[mf_][kk_], BF[nf_][kk_],                                  \
                acc[(MH) * 4 + mf_][(NH) * 2 + nf_], 0, 0, 0);               \
    __builtin_amdgcn_s_setprio(0);                                           \
  } while (0)

  f32x4 acc[8][4] = {};
  bf16x8 aH0[4][2], aH1[4][2], bH0[2][2], bH1[2][2];

  STG_HALF(0, Ag, 0, 0, 0);
  STG_HALF(1, Bg, 0, 0, 0);
  STG_HALF(1, Bg, 0, 1, 0);
  STG_HALF(0, Ag, 0, 1, 0);
  VMW(4);
  BARRIER();
  LDS_A(aH0, 0, 0);
  LDS_B(bH0, 0, 0);

  for (int t = 0; t < nt; ++t) {
    const int bc = t & 1, ob = bc ^ 1;
    const bool more = (t + 1 < nt);
    VMW(0);
    BARRIER();
    if (more) {
      STG_HALF(0, Ag, ob, 0, t + 1);
      STG_HALF(1, Bg, ob, 0, t + 1);
    }
    LDS_B(bH1, bc, 1);
    MFMA_C(0, 0, aH0, bH0);
    if (more) STG_HALF(1, Bg, ob, 1, t + 1);
    LDS_A(aH1, bc, 1);
    MFMA_C(0, 1, aH0, bH1);
    if (more) STG_HALF(0, Ag, ob, 1, t + 1);
    MFMA_C(1, 1, aH1, bH1);
    VMW(4);
    BARRIER();
    MFMA_C(1, 0, aH1, bH0);
    if (more) {
      LDS_A(aH0, ob, 0);
      LDS_B(bH0, ob, 0);
    }
  }

#pragma unroll
  for (int nh = 0; nh < 2; nh++)
#pragma unroll
    for (int nf = 0; nf < 2; nf++) {
      const int col = bn * 256 + nh * 128 + wn * 32 + nf * 16 + l15;
      const float bv = (MODE == 0) ? bias[col] : 0.f;
#pragma unroll
      for (int mh = 0; mh < 2; mh++)
#pragma unroll
        for (int mf = 0; mf < 4; mf++) {
          const int row0 = bm * 256 + mh * 128 + wm * 64 + mf * 16 + quad * 4;
#pragma unroll
          for (int r = 0; r < 4; r++) {
            float v = acc[mh * 4 + mf][nh * 2 + nf][r] + bv;
            if (ACT == 1) {
              const float tt = v * (0.7978845608f + 0.0356774081f * v * v);
              v = 0.5f * v * (1.0f + tanhf(tt));
            }
            if (MODE == 0)
              ((u16*)Cv)[(size_t)(row0 + r) * N + col] = f2us(v);
            else
              atomicAdd((float*)Cv + (size_t)(row0 + r) * N + col, v);
          }
        }
    }
#undef STG_HALF
#undef LDS_A
#undef LDS_B
#undef MFMA_C
}

// ---------------------------------------------------------------------------
// RoPE in-place on bf16 qkv (q and k sections, first 32 dims of each head).
// ---------------------------------------------------------------------------
__global__ void rope_kernel(u16* __restrict__ qkv, const int* __restrict__ pos) {
  const int idx = blockIdx.x * 256 + threadIdx.x;
  const int i = idx & 15;
  const int which = (idx >> 4) & 1;
  const int hh = (idx >> 5) & 31;
  const int s = idx >> 10;
  const float p = (float)pos[s];
  const float freq = p * expf(-0.57564627324851f * (float)i);
  float sn, c;
  sincosf(freq, &sn, &c);
  u16* base = qkv + (size_t)s * (3 * DMODEL) + which * DMODEL + hh * HDIM + i;
  const float t0 = us2f(base[0]), t1 = us2f(base[16]);
  base[0] = f2us(t0 * c - t1 * sn);
  base[16] = f2us(t1 * c + t0 * sn);
}

// ---------------------------------------------------------------------------
// Flash attention (causal), bf16. Grid (S/64, H), 256 thr = 4 waves; each
// wave owns 16 q-rows. KT=64 keys/iter, hd 80 padded to 96 (3 K=32 steps).
//
// Structure (round 6 intent, V-staging width FIXED):
//  - K/V double-buffered in LDS; ONE __syncthreads per iter.  Global loads
//    for tile t+1 issue BEFORE compute; ds_writes to buf[cur^1] after
//    compute.  WAR safe: buf[cur^1]'s last reads drained at the
//    end-of-previous-iter barrier.
//  - V transpose staging vectorized: 160 threads x {2 key-rows x 16 dims}.
//    Each row needs TWO uint4 (16 dims = 32B) — round-6 bug loaded one
//    uint4 and indexed A0[0..7] against a 4-dword array (UB, garbage V).
//    Packed write: dV[(cc*16+d)*44+p] = V[2p][d] | V[2p+1][d]<<16
//    (= Vts[d'*88 + 2p(+1)]); 2 lanes/bank = conflict-free.
//  - Q fragments hoisted; causal mask only on the diagonal tile.
// LDS: Qs 13.3K + 2xKs 26.6K + 2xVts 28.2K + Ps 10.2K = 78336 B
// -> 2 blocks/CU.
// ---------------------------------------------------------------------------
__global__ void attn_kernel(const u16* __restrict__ qkv, u16* __restrict__ y) {
  const int qt = (int)gridDim.x - 1 - (int)blockIdx.x;  // longest first
  const int h = blockIdx.y;
  const int tid = threadIdx.x, wave = tid >> 6, lane = tid & 63;
  const int quad = lane >> 4, l15 = lane & 15;
  const int qbase = qt * 64;

  __shared__ __align__(16) u16 Qs[64 * 104];
  __shared__ __align__(16) u16 Ks[2][64 * 104];
  __shared__ __align__(16) u16 Vts[2][80 * 88];  // [dim][key], stride 88
  __shared__ __align__(16) u16 Ps[4][2][16 * 40];

  // zero only the read pads: Ks[*] cols 80..95, Qs cols 80..103
  if (tid < 128) {
    const int b = tid >> 6, r = tid & 63;
    u16* z = &Ks[b][r * 104 + 80];
    *(uint4*)z = uint4{0, 0, 0, 0};
    *(uint4*)(z + 8) = uint4{0, 0, 0, 0};
  } else if (tid < 192) {
    const int r = tid & 63;
    u16* z = &Qs[r * 104 + 80];
    *(uint4*)z = uint4{0, 0, 0, 0};
    *(uint4*)(z + 8) = uint4{0, 0, 0, 0};
    *(uint4*)(z + 16) = uint4{0, 0, 0, 0};
  }

  {  // stage Q once, folding in 1/sqrt(80)
    const int r = tid >> 2, c = tid & 3;
    const u16* src = qkv + (size_t)(qbase + r) * (3 * DMODEL) + h * HDIM + c * 20;
    u16* dst = Qs + r * 104 + c * 20;
#pragma unroll
    for (int j = 0; j < 5; j++) {
      ushort4 uv = *(const ushort4*)(src + j * 4);
      ushort4 ov;
      ov.x = f2us(us2f(uv.x) * 0.11180339887f);
      ov.y = f2us(us2f(uv.y) * 0.11180339887f);
      ov.z = f2us(us2f(uv.z) * 0.11180339887f);
      ov.w = f2us(us2f(uv.w) * 0.11180339887f);
      *(ushort4*)(dst + j * 4) = ov;
    }
  }

  // stage tile 0 (K rows + V transposed) into buffer 0
  {
    const int r = tid >> 2, c4 = (tid & 3) * 20;
    const u16* sK = qkv + (size_t)r * (3 * DMODEL) + DMODEL + h * HDIM + c4;
    u16* dK = &Ks[0][r * 104 + c4];
#pragma unroll
    for (int j = 0; j < 5; j++) *(uint2*)(dK + j * 4) = *(const uint2*)(sK + j * 4);
  }
  if (tid < 160) {
    const int p = tid & 31, cc = tid >> 5;
    const u16* sV = qkv + (size_t)(2 * p) * (3 * DMODEL) + 2 * DMODEL + h * HDIM + cc * 16;
    const uint4 a0 = *(const uint4*)sV;
    const uint4 b0 = *(const uint4*)(sV + 8);
    const uint4 a1 = *(const uint4*)(sV + 3 * DMODEL);
    const uint4 b1 = *(const uint4*)(sV + 3 * DMODEL + 8);
    const uint32_t A0[8] = {a0.x, a0.y, a0.z, a0.w, b0.x, b0.y, b0.z, b0.w};
    const uint32_t A1[8] = {a1.x, a1.y, a1.z, a1.w, b1.x, b1.y, b1.z, b1.w};
    uint32_t* dV = (uint32_t*)Vts[0];
#pragma unroll
    for (int d = 0; d < 16; d++) {
      const int j = d >> 1, s = (d & 1) * 16;
      const uint32_t o = ((A0[j] >> s) & 0xffffu) | (((A1[j] >> s) & 0xffffu) << 16);
      dV[(cc * 16 + d) * 44 + p] = o;
    }
  }

  float m_i[4], l_i[4];
  f32x4 oacc[5] = {};
#pragma unroll
  for (int r = 0; r < 4; r++) { m_i[r] = -1e30f; l_i[r] = 0.f; }

  __syncthreads();

  // Q fragments are loop-invariant: hoist
  bf16x8 aq[3];
#pragma unroll
  for (int ks = 0; ks < 3; ks++)
    aq[ks] = *(const bf16x8*)&Qs[(wave * 16 + l15) * 104 + ks * 32 + quad * 8];

  const int n_iter = qt + 1;
  uint2 kr[5];
  uint4 v0a = {}, v0b = {}, v1a = {}, v1b = {};

  for (int it = 0; it < n_iter; ++it) {
    const int cur = it & 1;
    const bool more = (it + 1 < n_iter);
    // ---- prefetch tile t+1 into registers (global; latency hidden) ----
    if (more) {
      const int kcn = (it + 1) * 64;
      const int r = tid >> 2, c4 = (tid & 3) * 20;
      const u16* sK = qkv + (size_t)(kcn + r) * (3 * DMODEL) + DMODEL + h * HDIM + c4;
#pragma unroll
      for (int j = 0; j < 5; j++) kr[j] = *(const uint2*)(sK + j * 4);
      if (tid < 160) {
        const int p = tid & 31, cc = tid >> 5;
        const u16* sV =
            qkv + (size_t)(kcn + 2 * p) * (3 * DMODEL) + 2 * DMODEL + h * HDIM + cc * 16;
        v0a = *(const uint4*)sV;
        v0b = *(const uint4*)(sV + 8);
        v1a = *(const uint4*)(sV + 3 * DMODEL);
        v1b = *(const uint4*)(sV + 3 * DMODEL + 8);
      }
    }

    // ---- S = Q K^T on buf[cur] ----
    const int kc0 = it * 64;
    f32x4 st[4] = {};
#pragma unroll
    for (int ks = 0; ks < 3; ks++)
#pragma unroll
      for (int t = 0; t < 4; t++) {
        bf16x8 bk = *(const bf16x8*)&Ks[cur][(t * 16 + l15) * 104 + ks * 32 + quad * 8];
        st[t] = __builtin_amdgcn_mfma_f32_16x16x32_bf16(aq[ks], bk, st[t], 0, 0, 0);
      }

    // ---- mask (diagonal tile only) + online softmax ----
    float sv[4][4], mx[4];
    if (it == qt) {
#pragma unroll
      for (int r = 0; r < 4; r++) {
        const int qr = qbase + wave * 16 + quad * 4 + r;
#pragma unroll
        for (int t = 0; t < 4; t++) {
          const int kc = kc0 + t * 16 + l15;
          sv[t][r] = (kc <= qr) ? st[t][r] : -1e30f;
        }
      }
    } else {
#pragma unroll
      for (int r = 0; r < 4; r++)
#pragma unroll
        for (int t = 0; t < 4; t++) sv[t][r] = st[t][r];
    }
#pragma unroll
    for (int r = 0; r < 4; r++)
      mx[r] = fmaxf(fmaxf(sv[0][r], sv[1][r]), fmaxf(sv[2][r], sv[3][r]));
#pragma unroll
    for (int o = 1; o < 16; o <<= 1)
#pragma unroll
      for (int r = 0; r < 4; r++) mx[r] = fmaxf(mx[r], __shfl_xor(mx[r], o, 64));

    float alpha[4], rs[4];
#pragma unroll
    for (int r = 0; r < 4; r++) {
      const float mnew = fmaxf(m_i[r], mx[r]);
      alpha[r] = __expf(m_i[r] - mnew);
      m_i[r] = mnew;
      const float p0 = __expf(sv[0][r] - mnew);
      const float p1 = __expf(sv[1][r] - mnew);
      const float p2 = __expf(sv[2][r] - mnew);
      const float p3 = __expf(sv[3][r] - mnew);
      rs[r] = (p0 + p1) + (p2 + p3);
      const int ro = (quad * 4 + r) * 40;
      Ps[wave][0][ro + l15] = f2us(p0);
      Ps[wave][0][ro + 16 + l15] = f2us(p1);
      Ps[wave][1][ro + l15] = f2us(p2);
      Ps[wave][1][ro + 16 + l15] = f2us(p3);
    }
#pragma unroll
    for (int o = 1; o < 16; o <<= 1)
#pragma unroll
      for (int r = 0; r < 4; r++) rs[r] += __shfl_xor(rs[r], o, 64);
#pragma unroll
    for (int r = 0; r < 4; r++) l_i[r] = l_i[r] * alpha[r] + rs[r];
#pragma unroll
    for (int dt = 0; dt < 5; dt++)
#pragma unroll
      for (int r = 0; r < 4; r++) oacc[dt][r] *= alpha[r];

    // ---- O += P V (P via per-wave LDS round-trip; Ps is wave-private) ----
    bf16x8 pf0 = *(const bf16x8*)&Ps[wave][0][l15 * 40 + quad * 8];
    bf16x8 pf1 = *(const bf16x8*)&Ps[wave][1][l15 * 40 + quad * 8];
#pragma unroll
    for (int dt = 0; dt < 5; dt++) {
      bf16x8 vf0 = *(const bf16x8*)&Vts[cur][(dt * 16 + l15) * 88 + quad * 8];
      bf16x8 vf1 = *(const bf16x8*)&Vts[cur][(dt * 16 + l15) * 88 + 32 + quad * 8];
      oacc[dt] = __builtin_amdgcn_mfma_f32_16x16x32_bf16(pf0, vf0, oacc[dt], 0, 0, 0);
      oacc[dt] = __builtin_amdgcn_mfma_f32_16x16x32_bf16(pf1, vf1, oacc[dt], 0, 0, 0);
    }

    // ---- write prefetched tile t+1 into buf[cur^1] ----
    if (more) {
      const int r = tid >> 2, c4 = (tid & 3) * 20;
      u16* dK = &Ks[cur ^ 1][r * 104 + c4];
#pragma unroll
      for (int j = 0; j < 5; j++) *(uint2*)(dK + j * 4) = kr[j];
      if (tid < 160) {
        const int p = tid & 31, cc = tid >> 5;
        const uint32_t A0[8] = {v0a.x, v0a.y, v0a.z, v0a.w,
                                v0b.x, v0b.y, v0b.z, v0b.w};
        const uint32_t A1[8] = {v1a.x, v1a.y, v1a.z, v1a.w,
                                v1b.x, v1b.y, v1b.z, v1b.w};
        uint32_t* dV = (uint32_t*)Vts[cur ^ 1];
#pragma unroll
        for (int d = 0; d < 16; d++) {
          const int j = d >> 1, s = (d & 1) * 16;
          const uint32_t o =
              ((A0[j] >> s) & 0xffffu) | (((A1[j] >> s) & 0xffffu) << 16);
          dV[(cc * 16 + d) * 44 + p] = o;
        }
      }
    }
    __syncthreads();
  }

#pragma unroll
  for (int dt = 0; dt < 5; dt++)
#pragma unroll
    for (int r = 0; r < 4; r++) {
      const int row = qbase + wave * 16 + quad * 4 + r;
      y[(size_t)row * DMODEL + h * HDIM + dt * 16 + l15] = f2us(oacc[dt][r] / l_i[r]);
    }
}

extern "C" void kernel_launch(void* const* d_in, const int* in_sizes, int n_in,
                              void* d_out, int out_size, void* d_ws, size_t ws_size,
                              hipStream_t stream) {
  const float* x = (const float*)d_in[0];
  const int* pos = (const int*)d_in[1];
  const float* ln_w = (const float*)d_in[3];
  const float* ln_b = (const float*)d_in[4];
  const float* wqkv_w = (const float*)d_in[5];
  const float* wqkv_b = (const float*)d_in[6];
  const float* wo_w = (const float*)d_in[7];
  const float* wo_b = (const float*)d_in[8];
  const float* w1_w = (const float*)d_in[9];
  const float* w1_b = (const float*)d_in[10];
  const float* w2_w = (const float*)d_in[11];
  const float* w2_b = (const float*)d_in[12];
  float* out = (float*)d_out;

  char* ws = (char*)d_ws;
  // layout (100 MB):
  //   [0,        52428800)  wbuf (bf16 weights, reused 4x)
  //   [52428800, 62914560)  h bf16
  //   [62914560, 104857600) ffn1 bf16 (42MB) -> later qkv (31.5) + yAtt (10.5)
  u16* wbuf = (u16*)(ws);
  u16* h = (u16*)(ws + 52428800);
  u16* ffn1 = (u16*)(ws + 62914560);
  u16* qkv = (u16*)(ws + 62914560);
  u16* yAtt = (u16*)(ws + 94371840);

  ln_kernel<<<S_LEN, 256, 0, stream>>>(x, ln_w, ln_b, h);
  initout_kernel<<<(S_LEN * DMODEL / 4) / 256, 256, 0, stream>>>(x, wo_b, w2_b, out);

  // FFN branch (ffn1 dies before qkv overlays it)
  f2b_kernel<<<(DINTER * DMODEL) / 2048, 256, 0, stream>>>(w1_w, wbuf);
  gemm256<1, 0><<<dim3(DINTER / 256, S_LEN / 256, 1), 512, 0, stream>>>(
      h, wbuf, w1_b, ffn1, S_LEN, DINTER, DMODEL);
  f2b_kernel<<<(DMODEL * DINTER) / 2048, 256, 0, stream>>>(w2_w, wbuf);
  gemm256<0, 2><<<dim3(DMODEL / 256, S_LEN / 256, 5), 512, 0, stream>>>(
      ffn1, wbuf, w2_b, out, S_LEN, DMODEL, DINTER);

  // Attention branch
  f2b_kernel<<<(3 * DMODEL * DMODEL) / 2048, 256, 0, stream>>>(wqkv_w, wbuf);
  gemm256<0, 0><<<dim3(3 * DMODEL / 256, S_LEN / 256, 1), 512, 0, stream>>>(
      h, wbuf, wqkv_b, qkv, S_LEN, 3 * DMODEL, DMODEL);
  rope_kernel<<<(S_LEN * NHEADS * 2 * 16) / 256, 256, 0, stream>>>(qkv, pos);
  attn_kernel<<<dim3(S_LEN / 64, NHEADS), 256, 0, stream>>>(qkv, yAtt);
  f2b_kernel<<<(DMODEL * DMODEL) / 2048, 256, 0, stream>>>(wo_w, wbuf);
  gemm256<0, 2><<<dim3(DMODEL / 256, S_LEN / 256, 2), 512, 0, stream>>>(
      yAtt, wbuf, wo_b, out, S_LEN, DMODEL, DMODEL);
}